// Round 10
// baseline (494.112 us; speedup 1.0000x reference)
//
#include <hip/hip_runtime.h>
#include <cstdint>
#include <cstddef>

#define T_TOK 4096
#define DM 1024
#define DF 2048
#define NE 8
#define PADROWS 9216   // 72 tiles * 128
#define MAXTILES 72

typedef unsigned short u16;
typedef unsigned int u32;
using short8 = __attribute__((ext_vector_type(8))) short;   // 8 bf16 (4 VGPRs)
using f32x4  = __attribute__((ext_vector_type(4))) float;   // MFMA accum

// ---------------- ws layout (bytes) ----------------
static constexpr size_t OFF_H    = 0;                                   // x as bf16 [4096][1024]
static constexpr size_t OFF_WGT  = OFF_H   + (size_t)T_TOK * DM * 2;    // WgT bf16 [8][2048][1024] (scr bf16 overlay after gemm1)
static constexpr size_t OFF_WIT  = OFF_WGT + (size_t)NE * DM * DF * 2;  // WiT bf16 [8][2048][1024]
static constexpr size_t OFF_WOT  = OFF_WIT + (size_t)NE * DM * DF * 2;  // WoT bf16 [8][1024][2048]
static constexpr size_t OFF_A    = OFF_WOT + (size_t)NE * DF * DM * 2;  // A bf16 [9216][2048]
static constexpr size_t OFF_TOK  = OFF_A   + (size_t)PADROWS * DF * 2;  // tok_list int[9216]
static constexpr size_t OFF_WL   = OFF_TOK + PADROWS * 4;               // w_list f32[9216]
static constexpr size_t OFF_TEXP = OFF_WL  + PADROWS * 4;               // top idx int[4096*2]
static constexpr size_t OFF_TW   = OFF_TEXP + (size_t)T_TOK * 2 * 4;    // top w f32[4096*2]
static constexpr size_t OFF_CNT  = OFF_TW  + (size_t)T_TOK * 2 * 4;     // counts int[8]
static constexpr size_t OFF_CUR  = OFF_CNT + 64;                        // (unused)
static constexpr size_t OFF_NT   = OFF_CUR + 64;                        // n_tiles int
static constexpr size_t OFF_TE   = OFF_NT  + 64;                        // tile_e int[72]
static constexpr size_t OFF_TP   = OFF_TE  + 512;                       // tile_p0 int[72]
static constexpr size_t OFF_POS  = OFF_TP  + 512;                       // pos int[4096*2]

__device__ __forceinline__ u16 f2bf(float f) {
  u32 u = __builtin_bit_cast(u32, f);
  u += 0x7FFFu + ((u >> 16) & 1u);     // RNE
  return (u16)(u >> 16);
}
__device__ __forceinline__ float bf2f(u16 b) {
  u32 u = ((u32)b) << 16;
  return __builtin_bit_cast(float, u);
}

__device__ __forceinline__ void async16(const void* g, void* l) {
  __builtin_amdgcn_global_load_lds((__attribute__((address_space(1))) void*)(g),
                                   (__attribute__((address_space(3))) void*)(l),
                                   16, 0, 0);
}

// counted waits: N allows the N youngest loads to stay in flight.
#define VMW(N) asm volatile("s_waitcnt vmcnt(" #N ")" ::: "memory")
#define BAR() __builtin_amdgcn_s_barrier()

// ---------------- small kernels ----------------
__global__ void init_small_k(int* __restrict__ tok, float* __restrict__ wl,
                             int* __restrict__ cnt) {
  int i = blockIdx.x * 256 + threadIdx.x;
  if (i < PADROWS) { tok[i] = -1; wl[i] = 0.f; }
  if (i < NE) cnt[i] = 0;
}

// transpose+convert: [e][R][C] f32 -> [e][C][R] bf16 ; 64x64 tiles
__global__ void transpose_w_k(const float* __restrict__ Wg, const float* __restrict__ Wi,
                              const float* __restrict__ Wo, u16* __restrict__ wgT,
                              u16* __restrict__ wiT, u16* __restrict__ woT) {
  __shared__ u16 lT[64][65];   // lT[c][r]
  int bid = blockIdx.x;
  int mat = bid >> 12;
  int r = bid & 4095;
  const float* src; u16* dst; int R, C;
  if (mat == 0)      { src = Wg; dst = wgT; R = DM; C = DF; }
  else if (mat == 1) { src = Wi; dst = wiT; R = DM; C = DF; }
  else               { src = Wo; dst = woT; R = DF; C = DM; }
  int e = r >> 9;
  int rem = r & 511;
  int ctiles = C >> 6;
  int tr = rem / ctiles, tc = rem % ctiles;
  size_t eb = (size_t)e * R * C;
  int r0 = tr * 64, c0 = tc * 64;
  int wv = threadIdx.x >> 6, lane = threadIdx.x & 63;
#pragma unroll
  for (int it = 0; it < 16; ++it) {
    int rl = it * 4 + wv;
    float v = src[eb + (size_t)(r0 + rl) * C + c0 + lane];
    lT[lane][rl] = f2bf(v);
  }
  __syncthreads();
#pragma unroll
  for (int i = 0; i < 2; ++i) {
    const int cl = i * 32 + wv * 8 + (lane >> 3);
    const int b8 = (lane & 7) * 8;
    u16 tmp[8];
#pragma unroll
    for (int k = 0; k < 8; ++k) tmp[k] = lT[cl][b8 + k];
    *(short8*)&dst[eb + (size_t)(c0 + cl) * R + r0 + b8] = *(const short8*)tmp;
  }
}

// router (fused with x->bf16 convert): one wave per token
__global__ void router_k(const float* __restrict__ x, const float* __restrict__ Wr,
                         float* __restrict__ logits, int* __restrict__ texp,
                         float* __restrict__ tw, int* __restrict__ cnt,
                         u16* __restrict__ hbf) {
  int wv = threadIdx.x >> 6, lane = threadIdx.x & 63;
  int t = blockIdx.x * 4 + wv;
  const float* h = x + (size_t)t * DM;
  u16* hb = hbf + (size_t)t * DM;
  float acc[8] = {0.f, 0.f, 0.f, 0.f, 0.f, 0.f, 0.f, 0.f};
#pragma unroll
  for (int j = 0; j < 16; ++j) {
    float hv = h[lane + j * 64];
    hb[lane + j * 64] = f2bf(hv);
    const float4* wr = (const float4*)(Wr + (size_t)(lane + j * 64) * 8);
    float4 w0 = wr[0], w1 = wr[1];
    acc[0] += hv * w0.x; acc[1] += hv * w0.y; acc[2] += hv * w0.z; acc[3] += hv * w0.w;
    acc[4] += hv * w1.x; acc[5] += hv * w1.y; acc[6] += hv * w1.z; acc[7] += hv * w1.w;
  }
#pragma unroll
  for (int e = 0; e < 8; ++e)
#pragma unroll
    for (int off = 32; off > 0; off >>= 1) acc[e] += __shfl_down(acc[e], off, 64);
  if (lane == 0) {
    float mx = acc[0];
#pragma unroll
    for (int e = 1; e < 8; ++e) mx = fmaxf(mx, acc[e]);
    float p[8];
#pragma unroll
    for (int e = 0; e < 8; ++e) p[e] = __expf(acc[e] - mx);
    int i1 = 0; float b1 = p[0];
#pragma unroll
    for (int e = 1; e < 8; ++e) if (p[e] > b1) { b1 = p[e]; i1 = e; }
    int i2 = -1; float b2 = -1.f;
#pragma unroll
    for (int e = 0; e < 8; ++e) if (e != i1 && p[e] > b2) { b2 = p[e]; i2 = e; }
    float inv = 1.f / (b1 + b2);
    texp[t * 2] = i1; texp[t * 2 + 1] = i2;
    tw[t * 2] = b1 * inv; tw[t * 2 + 1] = b2 * inv;
    atomicAdd(&cnt[i1], 1); atomicAdd(&cnt[i2], 1);
#pragma unroll
    for (int e = 0; e < 8; ++e) logits[(size_t)t * 8 + e] = acc[e];
  }
}

// plan + scatter fused (single block, LDS cursors)
__global__ void plan_scatter_k(const int* __restrict__ cnt, const int* __restrict__ texp,
                               const float* __restrict__ tw, int* __restrict__ tile_e,
                               int* __restrict__ tile_p, int* __restrict__ ntiles,
                               int* __restrict__ tok, float* __restrict__ wl,
                               int* __restrict__ pos) {
  __shared__ int curs[NE];
  __shared__ int toff[NE + 1], roff[NE];
  if (threadIdx.x == 0) {
    int off = 0, nt = 0;
    for (int e = 0; e < NE; ++e) {
      int tt = (cnt[e] + 127) >> 7;
      curs[e] = off; toff[e] = nt; roff[e] = off;
      nt += tt; off += tt * 128;
    }
    toff[NE] = nt;
    *ntiles = nt;
  }
  __syncthreads();
  for (int idx = threadIdx.x; idx < MAXTILES; idx += 256) {
    int e = 0;
    while (e < NE && !(idx >= toff[e] && idx < toff[e + 1])) ++e;
    if (e < NE) { tile_e[idx] = e; tile_p[idx] = roff[e] + (idx - toff[e]) * 128; }
  }
  for (int t = threadIdx.x; t < T_TOK; t += 256) {
#pragma unroll
    for (int k = 0; k < 2; ++k) {
      int e = texp[t * 2 + k];
      int p = atomicAdd(&curs[e], 1);
      tok[p] = t;
      wl[p] = tw[t * 2 + k];
      pos[t * 2 + k] = p;
    }
  }
}

// ---------------- GEMM1: 128 rows x 64 f (dual gate+up), BK=64 ----------------
// H: 4-slot LDS ring (4 x 16KB), staged 2 tiles ahead via global_load_lds (swizzled both-sides).
// B (gate+up): global -> registers, double-buffered named sets, issued 1 tile ahead.
// Counted vmcnt(12) per tile (allows B(t+1)+H(t+2) in flight; H(t+1) is older => landed).
__global__ __launch_bounds__(256) void gemm1_k(
    const u16* __restrict__ hbf, const u16* __restrict__ wgT, const u16* __restrict__ wiT,
    const int* __restrict__ tok, const float* __restrict__ wl,
    const int* __restrict__ tile_e, const int* __restrict__ tile_p,
    const int* __restrict__ ntiles, u16* __restrict__ Aact) {
  __shared__ u16 smem[4 * 8192];   // 64KB: 4 H-slots of 128x64
  const int tile = blockIdx.y;
  if (tile >= *ntiles) return;
  const int e  = tile_e[tile];
  const int p0 = tile_p[tile];
  const int f0 = blockIdx.x * 64;
  const int tid = threadIdx.x, wv = tid >> 6, lane = tid & 63;

  // H staging sources (inverse-swizzled chunks): wave covers 32 rows, 4 issues x 8 rows
  const u16* hsrc[4];
  int hoff[4];
#pragma unroll
  for (int i = 0; i < 4; ++i) {
    const int row = wv * 32 + i * 8 + (lane >> 3);
    const int gc  = (lane & 7) ^ (row & 7);
    int tk  = tok[p0 + row];
    if (tk < 0) tk = 0;                        // pad rows: wl=0 zeroes the output
    hsrc[i] = hbf + (size_t)tk * DM + gc * 8;
    hoff[i] = (wv * 32 + i * 8) * 64;
  }

  const int wr = wv >> 1, wc = wv & 1;
  const int wrBase = wr * 64, wcBase = wc * 32;
  const int l4 = lane >> 4, ln = lane & 15;

  // B per-lane base pointers (fragment-direct: row f, k-chunk l4*8)
  const u16* bgb[2];
  const u16* bub[2];
#pragma unroll
  for (int n = 0; n < 2; ++n) {
    const size_t rowf = (size_t)(f0 + wcBase + n * 16 + ln);
    bgb[n] = wgT + (size_t)e * DM * DF + rowf * DM + l4 * 8;
    bub[n] = wiT + (size_t)e * DM * DF + rowf * DM + l4 * 8;
  }

  f32x4 accG[4][2], accU[4][2];
#pragma unroll
  for (int m = 0; m < 4; ++m)
#pragma unroll
    for (int n = 0; n < 2; ++n) { accG[m][n] = (f32x4)(0.f); accU[m][n] = (f32x4)(0.f); }

  short8 bg0[2][2], bu0[2][2], bg1[2][2], bu1[2][2];   // [n][s], named double buffer

  auto stageH = [&](int T) {
    u16* dst = smem + (T & 3) * 8192;
#pragma unroll
    for (int i = 0; i < 4; ++i) async16(hsrc[i] + (size_t)T * 64, dst + hoff[i]);
  };
  auto loadB = [&](short8 (&bg)[2][2], short8 (&bu)[2][2], int T) {
#pragma unroll
    for (int n = 0; n < 2; ++n)
#pragma unroll
      for (int s = 0; s < 2; ++s) {
        bg[n][s] = *(const short8*)(bgb[n] + (size_t)T * 64 + s * 32);
        bu[n][s] = *(const short8*)(bub[n] + (size_t)T * 64 + s * 32);
      }
  };
  auto comp = [&](const short8 (&bg)[2][2], const short8 (&bu)[2][2], int slot) {
    const u16* b = smem + slot * 8192;
    short8 a[4][2];
#pragma unroll
    for (int s = 0; s < 2; ++s) {
      const int c = s * 4 + l4;
#pragma unroll
      for (int m = 0; m < 4; ++m) {
        const int row = wrBase + m * 16 + ln;
        a[m][s] = *(const short8*)&b[row * 64 + ((c ^ (row & 7)) * 8)];
      }
    }
    __builtin_amdgcn_s_setprio(1);
#pragma unroll
    for (int s = 0; s < 2; ++s)
#pragma unroll
      for (int m = 0; m < 4; ++m)
#pragma unroll
        for (int n = 0; n < 2; ++n) {
          accG[m][n] = __builtin_amdgcn_mfma_f32_16x16x32_bf16(a[m][s], bg[n][s], accG[m][n], 0, 0, 0);
          accU[m][n] = __builtin_amdgcn_mfma_f32_16x16x32_bf16(a[m][s], bu[n][s], accU[m][n], 0, 0, 0);
        }
    __builtin_amdgcn_s_setprio(0);
  };

  // prologue: H0(4), B0(8), H1(4) -> wait first 12 (H0+B0), allow H1 in flight
  stageH(0);
  loadB(bg0, bu0, 0);
  stageH(1);
  VMW(4); BAR();

  for (int t = 0; t < 14; t += 2) {
    loadB(bg1, bu1, t + 1); stageH(t + 2);
    comp(bg0, bu0, t & 3);
    VMW(12); BAR();
    loadB(bg0, bu0, t + 2); stageH(t + 3);
    comp(bg1, bu1, (t + 1) & 3);
    VMW(12); BAR();
  }
  // tile 14 (uses bg0, loaded at t=12 second half)
  loadB(bg1, bu1, 15);
  comp(bg0, bu0, 2);
  VMW(8); BAR();
  // tile 15
  comp(bg1, bu1, 3);

  // epilogue: silu(g)*u*w -> LDS repack (stride 80, overlays slots 0-1) -> vector store
  u16* lOut = smem;
  BAR();
#pragma unroll
  for (int m = 0; m < 4; ++m)
#pragma unroll
    for (int j = 0; j < 4; ++j) {
      const int row = wrBase + m * 16 + l4 * 4 + j;   // C/D: row=(l>>4)*4+j
      const float w = wl[p0 + row];
#pragma unroll
      for (int n = 0; n < 2; ++n) {
        const float g = accG[m][n][j];
        const float u = accU[m][n][j];
        const float val = (g / (1.f + __expf(-g))) * u * w;
        lOut[row * 80 + wcBase + n * 16 + ln] = f2bf(val);
      }
    }
  __syncthreads();
  const int r = tid >> 1, hf = tid & 1;
  u16* gdst = Aact + (size_t)(p0 + r) * DF + f0 + hf * 32;
  const u16* lsrc = &lOut[r * 80 + hf * 32];
#pragma unroll
  for (int i = 0; i < 4; ++i)
    *(short8*)(gdst + i * 8) = *(const short8*)(lsrc + i * 8);
}

// ---------------- GEMM2: 128 rows x 64 d, K=2048, same ring+reg-B structure ----------------
__global__ __launch_bounds__(256) void gemm2_k(
    const u16* __restrict__ Aact, const u16* __restrict__ woT,
    const int* __restrict__ tile_e, const int* __restrict__ tile_p,
    const int* __restrict__ ntiles, u16* __restrict__ scr) {
  __shared__ u16 smem[4 * 8192];
  const int tile = blockIdx.y;
  if (tile >= *ntiles) return;
  const int e  = tile_e[tile];
  const int p0 = tile_p[tile];
  const int d0 = blockIdx.x * 64;
  const int tid = threadIdx.x, wv = tid >> 6, lane = tid & 63;

  const u16* asrc[4];
  int aoff[4];
#pragma unroll
  for (int i = 0; i < 4; ++i) {
    const int row = wv * 32 + i * 8 + (lane >> 3);
    const int gc  = (lane & 7) ^ (row & 7);
    asrc[i] = Aact + (size_t)(p0 + row) * DF + gc * 8;
    aoff[i] = (wv * 32 + i * 8) * 64;
  }

  const int wr = wv >> 1, wc = wv & 1;
  const int wrBase = wr * 64, wcBase = wc * 32;
  const int l4 = lane >> 4, ln = lane & 15;

  const u16* bwb[2];
#pragma unroll
  for (int n = 0; n < 2; ++n) {
    const size_t rowd = (size_t)(d0 + wcBase + n * 16 + ln);
    bwb[n] = woT + (size_t)e * DM * DF + rowd * DF + l4 * 8;
  }

  f32x4 acc[4][2];
#pragma unroll
  for (int m = 0; m < 4; ++m)
#pragma unroll
    for (int n = 0; n < 2; ++n) acc[m][n] = (f32x4)(0.f);

  short8 bw0[2][2], bw1[2][2];

  auto stageA = [&](int T) {
    u16* dst = smem + (T & 3) * 8192;
#pragma unroll
    for (int i = 0; i < 4; ++i) async16(asrc[i] + (size_t)T * 64, dst + aoff[i]);
  };
  auto loadB = [&](short8 (&bw)[2][2], int T) {
#pragma unroll
    for (int n = 0; n < 2; ++n)
#pragma unroll
      for (int s = 0; s < 2; ++s)
        bw[n][s] = *(const short8*)(bwb[n] + (size_t)T * 64 + s * 32);
  };
  auto comp = [&](const short8 (&bw)[2][2], int slot) {
    const u16* b = smem + slot * 8192;
    short8 a[4][2];
#pragma unroll
    for (int s = 0; s < 2; ++s) {
      const int c = s * 4 + l4;
#pragma unroll
      for (int m = 0; m < 4; ++m) {
        const int row = wrBase + m * 16 + ln;
        a[m][s] = *(const short8*)&b[row * 64 + ((c ^ (row & 7)) * 8)];
      }
    }
    __builtin_amdgcn_s_setprio(1);
#pragma unroll
    for (int s = 0; s < 2; ++s)
#pragma unroll
      for (int m = 0; m < 4; ++m)
#pragma unroll
        for (int n = 0; n < 2; ++n)
          acc[m][n] = __builtin_amdgcn_mfma_f32_16x16x32_bf16(a[m][s], bw[n][s], acc[m][n], 0, 0, 0);
    __builtin_amdgcn_s_setprio(0);
  };

  // prologue: A0(4), B0(4), A1(4) -> wait first 8, allow A1
  stageA(0);
  loadB(bw0, 0);
  stageA(1);
  VMW(4); BAR();

  for (int t = 0; t < 30; t += 2) {
    loadB(bw1, t + 1); stageA(t + 2);
    comp(bw0, t & 3);
    VMW(8); BAR();
    loadB(bw0, t + 2); stageA(t + 3);
    comp(bw1, (t + 1) & 3);
    VMW(8); BAR();
  }
  // tile 30 (uses bw0)
  loadB(bw1, 31);
  comp(bw0, 2);
  VMW(4); BAR();
  // tile 31
  comp(bw1, 3);

  // epilogue: bf16 repack (stride 72) -> vector store to scr
  u16* lOut = smem;
  BAR();
#pragma unroll
  for (int m = 0; m < 4; ++m)
#pragma unroll
    for (int j = 0; j < 4; ++j) {
      const int row = wrBase + m * 16 + l4 * 4 + j;
#pragma unroll
      for (int n = 0; n < 2; ++n)
        lOut[row * 72 + wcBase + n * 16 + ln] = f2bf(acc[m][n][j]);
    }
  __syncthreads();
  const int r = tid >> 1, hf = tid & 1;
  u16* gdst = scr + (size_t)(p0 + r) * DM + d0 + hf * 32;
  const u16* lsrc = &lOut[r * 72 + hf * 32];
#pragma unroll
  for (int i = 0; i < 4; ++i)
    *(short8*)(gdst + i * 8) = *(const short8*)(lsrc + i * 8);
}

// combine: out[t] = scr[pos1[t]] + scr[pos2[t]]  (bf16 scr -> f32 out)
__global__ void combine_k(const u16* __restrict__ scr, const int* __restrict__ pos,
                          float* __restrict__ out) {
  const int t = blockIdx.x;
  const int d = threadIdx.x;
  const int p1 = pos[t * 2], p2 = pos[t * 2 + 1];
  const ushort4 a = *(const ushort4*)(scr + (size_t)p1 * DM + d * 4);
  const ushort4 b = *(const ushort4*)(scr + (size_t)p2 * DM + d * 4);
  float4 o;
  o.x = bf2f(a.x) + bf2f(b.x);
  o.y = bf2f(a.y) + bf2f(b.y);
  o.z = bf2f(a.z) + bf2f(b.z);
  o.w = bf2f(a.w) + bf2f(b.w);
  *(float4*)(out + (size_t)t * DM + d * 4) = o;
}

// ---------------- launch ----------------
extern "C" void kernel_launch(void* const* d_in, const int* in_sizes, int n_in,
                              void* d_out, int out_size, void* d_ws, size_t ws_size,
                              hipStream_t stream) {
  const float* x  = (const float*)d_in[0];
  const float* Wr = (const float*)d_in[1];
  const float* Wg = (const float*)d_in[2];
  const float* Wi = (const float*)d_in[3];
  const float* Wo = (const float*)d_in[4];
  float* outF = (float*)d_out;
  float* logits = outF + (size_t)T_TOK * DM;

  char* ws = (char*)d_ws;
  u16*  hbf   = (u16*)(ws + OFF_H);
  u16*  wgT   = (u16*)(ws + OFF_WGT);
  u16*  wiT   = (u16*)(ws + OFF_WIT);
  u16*  woT   = (u16*)(ws + OFF_WOT);
  u16*  Aact  = (u16*)(ws + OFF_A);
  int*  tok   = (int*)(ws + OFF_TOK);
  float* wl   = (float*)(ws + OFF_WL);
  int*  texp  = (int*)(ws + OFF_TEXP);
  float* tw   = (float*)(ws + OFF_TW);
  int*  cnt   = (int*)(ws + OFF_CNT);
  int*  nt    = (int*)(ws + OFF_NT);
  int*  te    = (int*)(ws + OFF_TE);
  int*  tp    = (int*)(ws + OFF_TP);
  int*  pos   = (int*)(ws + OFF_POS);
  u16*  scr   = (u16*)(ws + OFF_WGT);   // bf16 scratch overlay on wgT (dead after gemm1)

  init_small_k<<<40, 256, 0, stream>>>(tok, wl, cnt);
  transpose_w_k<<<12288, 256, 0, stream>>>(Wg, Wi, Wo, wgT, wiT, woT);
  router_k<<<1024, 256, 0, stream>>>(x, Wr, logits, texp, tw, cnt, hbf);
  plan_scatter_k<<<1, 256, 0, stream>>>(cnt, texp, tw, te, tp, nt, tok, wl, pos);
  gemm1_k<<<dim3(DF / 64, MAXTILES), 256, 0, stream>>>(hbf, wgT, wiT, tok, wl, te, tp, nt, Aact);
  gemm2_k<<<dim3(DM / 64, MAXTILES), 256, 0, stream>>>(Aact, woT, te, tp, nt, scr);
  combine_k<<<4096, 256, 0, stream>>>(scr, pos, outF);
}

// Round 11
// 321.870 us; speedup vs baseline: 1.5351x; 1.5351x over previous
//
#include <hip/hip_runtime.h>
#include <cstdint>
#include <cstddef>

#define T_TOK 4096
#define DM 1024
#define DF 2048
#define NE 8
#define PADROWS 9216   // 72 tiles * 128
#define MAXTILES 72

typedef unsigned short u16;
typedef unsigned int u32;
using short8 = __attribute__((ext_vector_type(8))) short;   // 8 bf16 (4 VGPRs)
using f32x4  = __attribute__((ext_vector_type(4))) float;   // MFMA accum

// ---------------- ws layout (bytes) ----------------
static constexpr size_t OFF_H    = 0;                                   // x as bf16 [4096][1024]
static constexpr size_t OFF_WGT  = OFF_H   + (size_t)T_TOK * DM * 2;    // WgT bf16 [8][2048][1024] (scr bf16 overlay after gemm1)
static constexpr size_t OFF_WIT  = OFF_WGT + (size_t)NE * DM * DF * 2;  // WiT bf16 [8][2048][1024]
static constexpr size_t OFF_WOT  = OFF_WIT + (size_t)NE * DM * DF * 2;  // WoT bf16 [8][1024][2048]
static constexpr size_t OFF_A    = OFF_WOT + (size_t)NE * DF * DM * 2;  // A bf16 [9216][2048]
static constexpr size_t OFF_TOK  = OFF_A   + (size_t)PADROWS * DF * 2;  // tok_list int[9216]
static constexpr size_t OFF_WL   = OFF_TOK + PADROWS * 4;               // w_list f32[9216]
static constexpr size_t OFF_TEXP = OFF_WL  + PADROWS * 4;               // top idx int[4096*2]
static constexpr size_t OFF_TW   = OFF_TEXP + (size_t)T_TOK * 2 * 4;    // top w f32[4096*2]
static constexpr size_t OFF_CNT  = OFF_TW  + (size_t)T_TOK * 2 * 4;     // counts int[8]
static constexpr size_t OFF_CUR  = OFF_CNT + 64;                        // (unused)
static constexpr size_t OFF_NT   = OFF_CUR + 64;                        // n_tiles int
static constexpr size_t OFF_TE   = OFF_NT  + 64;                        // tile_e int[72]
static constexpr size_t OFF_TP   = OFF_TE  + 512;                       // tile_p0 int[72]
static constexpr size_t OFF_POS  = OFF_TP  + 512;                       // pos int[4096*2]

__device__ __forceinline__ u16 f2bf(float f) {
  u32 u = __builtin_bit_cast(u32, f);
  u += 0x7FFFu + ((u >> 16) & 1u);     // RNE
  return (u16)(u >> 16);
}
__device__ __forceinline__ float bf2f(u16 b) {
  u32 u = ((u32)b) << 16;
  return __builtin_bit_cast(float, u);
}

__device__ __forceinline__ void async16(const void* g, void* l) {
  __builtin_amdgcn_global_load_lds((__attribute__((address_space(1))) void*)(g),
                                   (__attribute__((address_space(3))) void*)(l),
                                   16, 0, 0);
}

// ---------------- transpose+convert: [e][R][C] f32 -> [e][C][R] bf16 ; 64x64 tiles ----------------
// block 0 additionally zeroes the router counters (router runs in a later dispatch on the
// same stream, so ordering is guaranteed; cnt must be re-zeroed every call for replay determinism)
__global__ void transpose_w_k(const float* __restrict__ Wg, const float* __restrict__ Wi,
                              const float* __restrict__ Wo, u16* __restrict__ wgT,
                              u16* __restrict__ wiT, u16* __restrict__ woT,
                              int* __restrict__ cnt) {
  if (blockIdx.x == 0 && threadIdx.x < NE) cnt[threadIdx.x] = 0;
  __shared__ u16 lT[64][65];   // lT[c][r]
  int bid = blockIdx.x;
  int mat = bid >> 12;
  int r = bid & 4095;
  const float* src; u16* dst; int R, C;
  if (mat == 0)      { src = Wg; dst = wgT; R = DM; C = DF; }
  else if (mat == 1) { src = Wi; dst = wiT; R = DM; C = DF; }
  else               { src = Wo; dst = woT; R = DF; C = DM; }
  int e = r >> 9;
  int rem = r & 511;
  int ctiles = C >> 6;
  int tr = rem / ctiles, tc = rem % ctiles;
  size_t eb = (size_t)e * R * C;
  int r0 = tr * 64, c0 = tc * 64;
  int wv = threadIdx.x >> 6, lane = threadIdx.x & 63;
#pragma unroll
  for (int it = 0; it < 16; ++it) {
    int rl = it * 4 + wv;
    float v = src[eb + (size_t)(r0 + rl) * C + c0 + lane];
    lT[lane][rl] = f2bf(v);
  }
  __syncthreads();
#pragma unroll
  for (int i = 0; i < 2; ++i) {
    const int cl = i * 32 + wv * 8 + (lane >> 3);
    const int b8 = (lane & 7) * 8;
    u16 tmp[8];
#pragma unroll
    for (int k = 0; k < 8; ++k) tmp[k] = lT[cl][b8 + k];
    *(short8*)&dst[eb + (size_t)(c0 + cl) * R + r0 + b8] = *(const short8*)tmp;
  }
}

// router (fused with x->bf16 convert): one wave per token
__global__ void router_k(const float* __restrict__ x, const float* __restrict__ Wr,
                         float* __restrict__ logits, int* __restrict__ texp,
                         float* __restrict__ tw, int* __restrict__ cnt,
                         u16* __restrict__ hbf) {
  int wv = threadIdx.x >> 6, lane = threadIdx.x & 63;
  int t = blockIdx.x * 4 + wv;
  const float* h = x + (size_t)t * DM;
  u16* hb = hbf + (size_t)t * DM;
  float acc[8] = {0.f, 0.f, 0.f, 0.f, 0.f, 0.f, 0.f, 0.f};
#pragma unroll
  for (int j = 0; j < 16; ++j) {
    float hv = h[lane + j * 64];
    hb[lane + j * 64] = f2bf(hv);
    const float4* wr = (const float4*)(Wr + (size_t)(lane + j * 64) * 8);
    float4 w0 = wr[0], w1 = wr[1];
    acc[0] += hv * w0.x; acc[1] += hv * w0.y; acc[2] += hv * w0.z; acc[3] += hv * w0.w;
    acc[4] += hv * w1.x; acc[5] += hv * w1.y; acc[6] += hv * w1.z; acc[7] += hv * w1.w;
  }
#pragma unroll
  for (int e = 0; e < 8; ++e)
#pragma unroll
    for (int off = 32; off > 0; off >>= 1) acc[e] += __shfl_down(acc[e], off, 64);
  if (lane == 0) {
    float mx = acc[0];
#pragma unroll
    for (int e = 1; e < 8; ++e) mx = fmaxf(mx, acc[e]);
    float p[8];
#pragma unroll
    for (int e = 0; e < 8; ++e) p[e] = __expf(acc[e] - mx);
    int i1 = 0; float b1 = p[0];
#pragma unroll
    for (int e = 1; e < 8; ++e) if (p[e] > b1) { b1 = p[e]; i1 = e; }
    int i2 = -1; float b2 = -1.f;
#pragma unroll
    for (int e = 0; e < 8; ++e) if (e != i1 && p[e] > b2) { b2 = p[e]; i2 = e; }
    float inv = 1.f / (b1 + b2);
    texp[t * 2] = i1; texp[t * 2 + 1] = i2;
    tw[t * 2] = b1 * inv; tw[t * 2 + 1] = b2 * inv;
    atomicAdd(&cnt[i1], 1); atomicAdd(&cnt[i2], 1);
#pragma unroll
    for (int e = 0; e < 8; ++e) logits[(size_t)t * 8 + e] = acc[e];
  }
}

// plan + init + scatter fused (single block, LDS cursors)
__global__ void plan_scatter_k(const int* __restrict__ cnt, const int* __restrict__ texp,
                               const float* __restrict__ tw, int* __restrict__ tile_e,
                               int* __restrict__ tile_p, int* __restrict__ ntiles,
                               int* __restrict__ tok, float* __restrict__ wl,
                               int* __restrict__ pos) {
  __shared__ int curs[NE];
  __shared__ int toff[NE + 1], roff[NE];
  // defaults for pad rows (re-written every call; ws is not re-poisoned between replays)
  for (int i = threadIdx.x; i < PADROWS; i += 256) { tok[i] = -1; wl[i] = 0.f; }
  if (threadIdx.x == 0) {
    int off = 0, nt = 0;
    for (int e = 0; e < NE; ++e) {
      int tt = (cnt[e] + 127) >> 7;
      curs[e] = off; toff[e] = nt; roff[e] = off;
      nt += tt; off += tt * 128;
    }
    toff[NE] = nt;
    *ntiles = nt;
  }
  __syncthreads();
  for (int idx = threadIdx.x; idx < MAXTILES; idx += 256) {
    int e = 0;
    while (e < NE && !(idx >= toff[e] && idx < toff[e + 1])) ++e;
    if (e < NE) { tile_e[idx] = e; tile_p[idx] = roff[e] + (idx - toff[e]) * 128; }
  }
  for (int t = threadIdx.x; t < T_TOK; t += 256) {
#pragma unroll
    for (int k = 0; k < 2; ++k) {
      int e = texp[t * 2 + k];
      int p = atomicAdd(&curs[e], 1);
      tok[p] = t;
      wl[p] = tw[t * 2 + k];
      pos[t * 2 + k] = p;
    }
  }
}

// ---------------- GEMM1: 128 rows x 64 f (dual gate+up), BK=64, 2-phase LDS dbuf ----------------
// Per-buffer LDS layout (u16 units): [0,8192) = H tile 128x64 ; [8192,12288) = gate B 64x64 ;
// [12288,16384) = up B 64x64. Two buffers (64KB). Epilogue overlays lOut[128][80] u16 (20.5KB).
__global__ __launch_bounds__(256) void gemm1_k(
    const u16* __restrict__ hbf, const u16* __restrict__ wgT, const u16* __restrict__ wiT,
    const int* __restrict__ tok, const float* __restrict__ wl,
    const int* __restrict__ tile_e, const int* __restrict__ tile_p,
    const int* __restrict__ ntiles, u16* __restrict__ Aact) {
  __shared__ char smem[65536];
  const int tile = blockIdx.y;
  if (tile >= *ntiles) return;
  const int e  = tile_e[tile];
  const int p0 = tile_p[tile];
  const int f0 = blockIdx.x * 64;
  const int tid = threadIdx.x, wv = tid >> 6, lane = tid & 63;

  // A staging: wave covers 32 rows (4 issues x 8 rows); source chunk pre-swizzled (c ^ row&7)
  const u16* hsrc[4];
  int hoff[4];
#pragma unroll
  for (int i = 0; i < 4; ++i) {
    const int row = wv * 32 + i * 8 + (lane >> 3);
    const int gc  = (lane & 7) ^ (row & 7);
    int tk  = tok[p0 + row];
    if (tk < 0) tk = 0;                        // pad rows: wl=0 zeroes the output
    hsrc[i] = hbf + (size_t)tk * DM + gc * 8;
    hoff[i] = (wv * 32 + i * 8) * 64;
  }
  // B staging: waves 0,1 -> gate rows 0-31/32-63 ; waves 2,3 -> up rows 0-31/32-63
  const u16* wbase = ((wv < 2) ? wgT : wiT) + (size_t)e * DM * DF;
  const int half = wv & 1, mt = wv >> 1;
  const u16* bsrc[4];
  int boff[4];
#pragma unroll
  for (int i = 0; i < 4; ++i) {
    const int row = half * 32 + i * 8 + (lane >> 3);
    const int gc  = (lane & 7) ^ (row & 7);
    bsrc[i] = wbase + (size_t)(f0 + row) * DM + gc * 8;
    boff[i] = 8192 + mt * 4096 + (half * 32 + i * 8) * 64;
  }

  f32x4 accG[4][2], accU[4][2];
#pragma unroll
  for (int m = 0; m < 4; ++m)
#pragma unroll
    for (int n = 0; n < 2; ++n) { accG[m][n] = (f32x4)(0.f); accU[m][n] = (f32x4)(0.f); }

  const int wr = wv >> 1, wc = wv & 1;
  const int wrBase = wr * 64, wcBase = wc * 32;
  const int l4 = lane >> 4, ln = lane & 15;

  // prologue: stage K-tile 0 into buffer 0
  {
    u16* b = (u16*)smem;
#pragma unroll
    for (int i = 0; i < 4; ++i) async16(hsrc[i], b + hoff[i]);
#pragma unroll
    for (int i = 0; i < 4; ++i) async16(bsrc[i], b + boff[i]);
  }
  __syncthreads();

  int cur = 0;
  for (int kt = 0; kt < DM / 64; ++kt) {
    // issue next tile's loads into the other buffer (overlap with compute below)
    if (kt < DM / 64 - 1) {
      u16* b = (u16*)smem + (cur ^ 1) * 16384;
#pragma unroll
      for (int i = 0; i < 4; ++i) async16(hsrc[i] + (size_t)(kt + 1) * 64, b + hoff[i]);
#pragma unroll
      for (int i = 0; i < 4; ++i) async16(bsrc[i] + (size_t)(kt + 1) * 64, b + boff[i]);
    }
    const u16* b = (const u16*)smem + cur * 16384;
#pragma unroll
    for (int s = 0; s < 2; ++s) {
      const int c = s * 4 + l4;
      short8 a[4], bg[2], bu[2];
#pragma unroll
      for (int m = 0; m < 4; ++m) {
        const int row = wrBase + m * 16 + ln;
        a[m] = *(const short8*)&b[row * 64 + ((c ^ (row & 7)) * 8)];
      }
#pragma unroll
      for (int n = 0; n < 2; ++n) {
        const int rowb = wcBase + n * 16 + ln;
        const int so = rowb * 64 + ((c ^ (rowb & 7)) * 8);
        bg[n] = *(const short8*)&b[8192 + so];
        bu[n] = *(const short8*)&b[12288 + so];
      }
#pragma unroll
      for (int m = 0; m < 4; ++m)
#pragma unroll
        for (int n = 0; n < 2; ++n) {
          accG[m][n] = __builtin_amdgcn_mfma_f32_16x16x32_bf16(a[m], bg[n], accG[m][n], 0, 0, 0);
          accU[m][n] = __builtin_amdgcn_mfma_f32_16x16x32_bf16(a[m], bu[n], accU[m][n], 0, 0, 0);
        }
    }
    __syncthreads();   // drains vmcnt (next tile landed) + protects buffer reuse
    cur ^= 1;
  }

  // epilogue: silu(g)*u*w -> LDS repack (stride 80 u16: 16B-aligned rows) -> vector store
  u16* lOut = (u16*)smem;
#pragma unroll
  for (int m = 0; m < 4; ++m)
#pragma unroll
    for (int j = 0; j < 4; ++j) {
      const int row = wrBase + m * 16 + l4 * 4 + j;   // C/D: row=(l>>4)*4+j
      const float w = wl[p0 + row];
#pragma unroll
      for (int n = 0; n < 2; ++n) {
        const float g = accG[m][n][j];
        const float u = accU[m][n][j];
        const float val = (g / (1.f + __expf(-g))) * u * w;
        lOut[row * 80 + wcBase + n * 16 + ln] = f2bf(val);
      }
    }
  __syncthreads();
  const int r = tid >> 1, hf = tid & 1;
  u16* gdst = Aact + (size_t)(p0 + r) * DF + f0 + hf * 32;
  const u16* lsrc = &lOut[r * 80 + hf * 32];
#pragma unroll
  for (int i = 0; i < 4; ++i)
    *(short8*)(gdst + i * 8) = *(const short8*)(lsrc + i * 8);
}

// ---------------- GEMM2: 128 rows x 64 d, K=2048, 2-phase dbuf; bf16 repack -> scr ----------------
// Per-buffer LDS (u16): [0,8192) = A 128x64 ; [8192,12288) = Wo 64x64. Two buffers (48KB).
__global__ __launch_bounds__(256) void gemm2_k(
    const u16* __restrict__ Aact, const u16* __restrict__ woT,
    const int* __restrict__ tile_e, const int* __restrict__ tile_p,
    const int* __restrict__ ntiles, u16* __restrict__ scr) {
  __shared__ char smem[49152];
  const int tile = blockIdx.y;
  if (tile >= *ntiles) return;
  const int e  = tile_e[tile];
  const int p0 = tile_p[tile];
  const int d0 = blockIdx.x * 64;
  const int tid = threadIdx.x, wv = tid >> 6, lane = tid & 63;

  const u16* asrc[4];
  int aoff[4];
#pragma unroll
  for (int i = 0; i < 4; ++i) {
    const int row = wv * 32 + i * 8 + (lane >> 3);
    const int gc  = (lane & 7) ^ (row & 7);
    asrc[i] = Aact + (size_t)(p0 + row) * DF + gc * 8;
    aoff[i] = (wv * 32 + i * 8) * 64;
  }
  const u16* wb = woT + (size_t)e * DM * DF;   // [d][f]
  const u16* wsrc[2];
  int woff[2];
#pragma unroll
  for (int i = 0; i < 2; ++i) {
    const int row = wv * 16 + i * 8 + (lane >> 3);
    const int gc  = (lane & 7) ^ (row & 7);
    wsrc[i] = wb + (size_t)(d0 + row) * DF + gc * 8;
    woff[i] = 8192 + (wv * 16 + i * 8) * 64;
  }

  f32x4 acc[4][2];
#pragma unroll
  for (int m = 0; m < 4; ++m)
#pragma unroll
    for (int n = 0; n < 2; ++n) acc[m][n] = (f32x4)(0.f);

  const int wr = wv >> 1, wc = wv & 1;
  const int wrBase = wr * 64, wcBase = wc * 32;
  const int l4 = lane >> 4, ln = lane & 15;

  {
    u16* b = (u16*)smem;
#pragma unroll
    for (int i = 0; i < 4; ++i) async16(asrc[i], b + aoff[i]);
#pragma unroll
    for (int i = 0; i < 2; ++i) async16(wsrc[i], b + woff[i]);
  }
  __syncthreads();

  int cur = 0;
  for (int kt = 0; kt < DF / 64; ++kt) {
    if (kt < DF / 64 - 1) {
      u16* b = (u16*)smem + (cur ^ 1) * 12288;
#pragma unroll
      for (int i = 0; i < 4; ++i) async16(asrc[i] + (size_t)(kt + 1) * 64, b + aoff[i]);
#pragma unroll
      for (int i = 0; i < 2; ++i) async16(wsrc[i] + (size_t)(kt + 1) * 64, b + woff[i]);
    }
    const u16* b = (const u16*)smem + cur * 12288;
#pragma unroll
    for (int s = 0; s < 2; ++s) {
      const int c = s * 4 + l4;
      short8 a[4], bw[2];
#pragma unroll
      for (int m = 0; m < 4; ++m) {
        const int row = wrBase + m * 16 + ln;
        a[m] = *(const short8*)&b[row * 64 + ((c ^ (row & 7)) * 8)];
      }
#pragma unroll
      for (int n = 0; n < 2; ++n) {
        const int rowb = wcBase + n * 16 + ln;
        bw[n] = *(const short8*)&b[8192 + rowb * 64 + ((c ^ (rowb & 7)) * 8)];
      }
#pragma unroll
      for (int m = 0; m < 4; ++m)
#pragma unroll
        for (int n = 0; n < 2; ++n)
          acc[m][n] = __builtin_amdgcn_mfma_f32_16x16x32_bf16(a[m], bw[n], acc[m][n], 0, 0, 0);
    }
    __syncthreads();
    cur ^= 1;
  }

  // epilogue: bf16 repack (stride 72 u16, 16B-aligned rows) -> vector store to scr
  u16* lOut = (u16*)smem;
#pragma unroll
  for (int m = 0; m < 4; ++m)
#pragma unroll
    for (int j = 0; j < 4; ++j) {
      const int row = wrBase + m * 16 + l4 * 4 + j;
#pragma unroll
      for (int n = 0; n < 2; ++n)
        lOut[row * 72 + wcBase + n * 16 + ln] = f2bf(acc[m][n][j]);
    }
  __syncthreads();
  const int r = tid >> 1, hf = tid & 1;
  u16* gdst = scr + (size_t)(p0 + r) * DM + d0 + hf * 32;
  const u16* lsrc = &lOut[r * 72 + hf * 32];
#pragma unroll
  for (int i = 0; i < 4; ++i)
    *(short8*)(gdst + i * 8) = *(const short8*)(lsrc + i * 8);
}

// combine: out[t] = scr[pos1[t]] + scr[pos2[t]]  (bf16 scr -> f32 out)
__global__ void combine_k(const u16* __restrict__ scr, const int* __restrict__ pos,
                          float* __restrict__ out) {
  const int t = blockIdx.x;
  const int d = threadIdx.x;
  const int p1 = pos[t * 2], p2 = pos[t * 2 + 1];
  const ushort4 a = *(const ushort4*)(scr + (size_t)p1 * DM + d * 4);
  const ushort4 b = *(const ushort4*)(scr + (size_t)p2 * DM + d * 4);
  float4 o;
  o.x = bf2f(a.x) + bf2f(b.x);
  o.y = bf2f(a.y) + bf2f(b.y);
  o.z = bf2f(a.z) + bf2f(b.z);
  o.w = bf2f(a.w) + bf2f(b.w);
  *(float4*)(out + (size_t)t * DM + d * 4) = o;
}

// ---------------- launch ----------------
extern "C" void kernel_launch(void* const* d_in, const int* in_sizes, int n_in,
                              void* d_out, int out_size, void* d_ws, size_t ws_size,
                              hipStream_t stream) {
  const float* x  = (const float*)d_in[0];
  const float* Wr = (const float*)d_in[1];
  const float* Wg = (const float*)d_in[2];
  const float* Wi = (const float*)d_in[3];
  const float* Wo = (const float*)d_in[4];
  float* outF = (float*)d_out;
  float* logits = outF + (size_t)T_TOK * DM;

  char* ws = (char*)d_ws;
  u16*  hbf   = (u16*)(ws + OFF_H);
  u16*  wgT   = (u16*)(ws + OFF_WGT);
  u16*  wiT   = (u16*)(ws + OFF_WIT);
  u16*  woT   = (u16*)(ws + OFF_WOT);
  u16*  Aact  = (u16*)(ws + OFF_A);
  int*  tok   = (int*)(ws + OFF_TOK);
  float* wl   = (float*)(ws + OFF_WL);
  int*  texp  = (int*)(ws + OFF_TEXP);
  float* tw   = (float*)(ws + OFF_TW);
  int*  cnt   = (int*)(ws + OFF_CNT);
  int*  nt    = (int*)(ws + OFF_NT);
  int*  te    = (int*)(ws + OFF_TE);
  int*  tp    = (int*)(ws + OFF_TP);
  int*  pos   = (int*)(ws + OFF_POS);
  u16*  scr   = (u16*)(ws + OFF_WGT);   // bf16 scratch overlay on wgT (dead after gemm1)

  transpose_w_k<<<12288, 256, 0, stream>>>(Wg, Wi, Wo, wgT, wiT, woT, cnt);
  router_k<<<1024, 256, 0, stream>>>(x, Wr, logits, texp, tw, cnt, hbf);
  plan_scatter_k<<<1, 256, 0, stream>>>(cnt, texp, tw, te, tp, nt, tok, wl, pos);
  gemm1_k<<<dim3(DF / 64, MAXTILES), 256, 0, stream>>>(hbf, wgT, wiT, tok, wl, te, tp, nt, Aact);
  gemm2_k<<<dim3(DM / 64, MAXTILES), 256, 0, stream>>>(Aact, woT, te, tp, nt, scr);
  combine_k<<<4096, 256, 0, stream>>>(scr, pos, outF);
}